// Round 11
// baseline (112.749 us; speedup 1.0000x reference)
//
#include <hip/hip_runtime.h>
#include <hip/hip_bf16.h>

#define N1   15996   // conv1 out length (batch 0, channel 0 row)
#define N2   5328    // conv2 out length
#define NG2  5584    // g2 window: max flat2 index 255+3+3*1775 = 5583
#define NJ   100
#define CLS  10

// ROUND 11: faithful-as-written semantics (R4's 4x-verified literal pipeline).
// SINGLE CHANGE: output dtype fp32 (writes all 2560 floats).
// R10 forensics: d_out is fp32; all prior bf16 writes covered only half the
// buffer, flooring absmax at max|ref[1280:]| = 3.03125 regardless of content.

// K1: y1[n] = relu(conv1(x)[0,0,n])
__global__ __launch_bounds__(256)
void k1_conv1(const float* __restrict__ x, const float* __restrict__ w1,
              const float* __restrict__ b1, float* __restrict__ y1)
{
    int n = blockIdx.x * 256 + threadIdx.x;
    if (n >= N1) return;
    float acc = b1[0];
    #pragma unroll
    for (int k = 0; k < 5; ++k) acc += x[n + k] * w1[k];
    y1[n] = fmaxf(acc, 0.f);
}

// K2: g[n] = max_d y1[n+d-3] - (d-3)^2 / (4*t1[0])
__global__ __launch_bounds__(256)
void k2_dil1(const float* __restrict__ y1, const float* __restrict__ t1,
             float* __restrict__ g)
{
    int n = blockIdx.x * 256 + threadIdx.x;
    if (n >= N1) return;
    float inv4t = 1.f / (4.f * t1[0]);
    float m = -INFINITY;
    #pragma unroll
    for (int d = 0; d < 7; ++d) {
        int p = n + d - 3;
        if ((unsigned)p < (unsigned)N1) {
            float z = (float)(d - 3);
            m = fmaxf(m, y1[p] - z * z * inv4t);
        }
    }
    g[n] = m;
}

// K3: y2[o*N2+m] = relu(b2[o] + sum_{i<2,k<5} g[i + 3*(m+k)] * w2[(o*2+i)*5+k]), o<2
__global__ __launch_bounds__(256)
void k3_conv2(const float* __restrict__ g, const float* __restrict__ w2,
              const float* __restrict__ b2, float* __restrict__ y2)
{
    int idx = blockIdx.x * 256 + threadIdx.x;
    if (idx >= 2 * N2) return;
    int o = idx / N2, m = idx % N2;
    float acc = b2[o];
    #pragma unroll
    for (int k = 0; k < 5; ++k) {
        #pragma unroll
        for (int i = 0; i < 2; ++i)
            acc += g[i + 3 * (m + k)] * w2[(o * 2 + i) * 5 + k];
    }
    y2[idx] = fmaxf(acc, 0.f);
}

// K4: g2[j] = max_d y2[c*N2 + p+d-3] - (d-3)^2/(4*t2[c]),  c=j/N2, p=j%N2
__global__ __launch_bounds__(256)
void k4_dil2(const float* __restrict__ y2, const float* __restrict__ t2,
             float* __restrict__ g2)
{
    int j = blockIdx.x * 256 + threadIdx.x;
    if (j >= NG2) return;
    int c = j / N2, p = j % N2;
    float inv4t = 1.f / (4.f * t2[c]);
    float m = -INFINITY;
    #pragma unroll
    for (int d = 0; d < 7; ++d) {
        int q = p + d - 3;
        if ((unsigned)q < (unsigned)N2) {
            float z = (float)(d - 3);
            m = fmaxf(m, y2[c * N2 + q] - z * z * inv4t);
        }
    }
    g2[j] = m;
}

// K5: block b: feat[b, c*1776+k] = g2[b + c + 3k]; thread t<100 computes a1[t]
// serially; then fc2 + log_softmax. OUTPUT FP32.
__global__ __launch_bounds__(256)
void k5_fc(const float* __restrict__ g2, const float* __restrict__ W1,
           const float* __restrict__ fb1, const float* __restrict__ W2,
           const float* __restrict__ fb2, float* __restrict__ out)
{
    __shared__ float gs[NG2];
    __shared__ float a1[NJ];
    __shared__ float a2[CLS];
    const int tid = threadIdx.x;
    const int b   = blockIdx.x;

    for (int i = tid; i < NG2; i += 256) gs[i] = g2[i];
    __syncthreads();

    if (tid < NJ) {
        float acc = fb1[tid];
        const float* w = W1 + (size_t)tid * 7104;
        for (int c = 0; c < 4; ++c)
            for (int k = 0; k < 1776; ++k)
                acc += gs[b + c + 3 * k] * w[c * 1776 + k];
        a1[tid] = fmaxf(acc, 0.f);
    }
    __syncthreads();

    if (tid < CLS) {
        float acc = fb2[tid];
        for (int j = 0; j < NJ; ++j) acc += a1[j] * W2[tid * NJ + j];
        a2[tid] = acc;
    }
    __syncthreads();

    if (tid < CLS) {
        float mx = -INFINITY;
        #pragma unroll
        for (int n = 0; n < CLS; ++n) mx = fmaxf(mx, a2[n]);
        float s = 0.f;
        #pragma unroll
        for (int n = 0; n < CLS; ++n) s += expf(a2[n] - mx);
        out[b * CLS + tid] = a2[tid] - mx - logf(s);   // FP32 OUTPUT
    }
}

extern "C" void kernel_launch(void* const* d_in, const int* in_sizes, int n_in,
                              void* d_out, int out_size, void* d_ws, size_t ws_size,
                              hipStream_t stream)
{
    const float* x   = (const float*)d_in[0];
    const float* w1  = (const float*)d_in[1];
    const float* b1  = (const float*)d_in[2];
    const float* t1  = (const float*)d_in[3];
    const float* w2  = (const float*)d_in[4];
    const float* b2  = (const float*)d_in[5];
    const float* t2  = (const float*)d_in[6];
    const float* fw1 = (const float*)d_in[7];
    const float* fb1 = (const float*)d_in[8];
    const float* fw2 = (const float*)d_in[9];
    const float* fb2 = (const float*)d_in[10];

    float* ws = (float*)d_ws;
    float* y1 = ws;                       // [N1]
    float* g  = ws + N1;                  // [N1]
    float* y2 = ws + 2 * N1;              // [2*N2]
    float* g2 = ws + 2 * N1 + 2 * N2;     // [NG2]   total 193 KB

    k1_conv1<<<(N1 + 255) / 256, 256, 0, stream>>>(x, w1, b1, y1);
    k2_dil1 <<<(N1 + 255) / 256, 256, 0, stream>>>(y1, t1, g);
    k3_conv2<<<(2 * N2 + 255) / 256, 256, 0, stream>>>(g, w2, b2, y2);
    k4_dil2 <<<(NG2 + 255) / 256, 256, 0, stream>>>(y2, t2, g2);
    k5_fc   <<<256, 256, 0, stream>>>(g2, fw1, fb1, fw2, fb2, (float*)d_out);
}

// Round 12
// 51.597 us; speedup vs baseline: 2.1852x; 2.1852x over previous
//
#include <hip/hip_runtime.h>
#include <hip/hip_bf16.h>

#define N1   15996   // conv1 out length (batch 0, channel 0 row)
#define N2   5328    // conv2 out length
#define NG2  5584    // g2 window: max flat2 index 255+3+3*1775 = 5583
#define NJ   100
#define CLS  10
#define NMC  64      // m-chunks for fc1
#define MCH  111     // 7104/64; 16*111 = 1776 so chunks never cross c-boundary
#define MROW 112     // padded LDS row stride (16B-aligned float4 rows)

// ---- prep (verified green in R11, unchanged) ----

__global__ __launch_bounds__(256)
void k1_conv1(const float* __restrict__ x, const float* __restrict__ w1,
              const float* __restrict__ b1, float* __restrict__ y1)
{
    int n = blockIdx.x * 256 + threadIdx.x;
    if (n >= N1) return;
    float acc = b1[0];
    #pragma unroll
    for (int k = 0; k < 5; ++k) acc += x[n + k] * w1[k];
    y1[n] = fmaxf(acc, 0.f);
}

__global__ __launch_bounds__(256)
void k2_dil1(const float* __restrict__ y1, const float* __restrict__ t1,
             float* __restrict__ g)
{
    int n = blockIdx.x * 256 + threadIdx.x;
    if (n >= N1) return;
    float inv4t = 1.f / (4.f * t1[0]);
    float m = -INFINITY;
    #pragma unroll
    for (int d = 0; d < 7; ++d) {
        int p = n + d - 3;
        if ((unsigned)p < (unsigned)N1) {
            float z = (float)(d - 3);
            m = fmaxf(m, y1[p] - z * z * inv4t);
        }
    }
    g[n] = m;
}

__global__ __launch_bounds__(256)
void k3_conv2(const float* __restrict__ g, const float* __restrict__ w2,
              const float* __restrict__ b2, float* __restrict__ y2)
{
    int idx = blockIdx.x * 256 + threadIdx.x;
    if (idx >= 2 * N2) return;
    int o = idx / N2, m = idx % N2;
    float acc = b2[o];
    #pragma unroll
    for (int k = 0; k < 5; ++k) {
        #pragma unroll
        for (int i = 0; i < 2; ++i)
            acc += g[i + 3 * (m + k)] * w2[(o * 2 + i) * 5 + k];
    }
    y2[idx] = fmaxf(acc, 0.f);
}

__global__ __launch_bounds__(256)
void k4_dil2(const float* __restrict__ y2, const float* __restrict__ t2,
             float* __restrict__ g2)
{
    int j = blockIdx.x * 256 + threadIdx.x;
    if (j >= NG2) return;
    int c = j / N2, p = j % N2;
    float inv4t = 1.f / (4.f * t2[c]);
    float m = -INFINITY;
    #pragma unroll
    for (int d = 0; d < 7; ++d) {
        int q = p + d - 3;
        if ((unsigned)q < (unsigned)N2) {
            float z = (float)(d - 3);
            m = fmaxf(m, y2[c * N2 + q] - z * z * inv4t);
        }
    }
    g2[j] = m;
}

// ---- fc1 outer-product: lane = batch, wave = 25 j's, block = (bt, mc) ----
// feat[b, m] = g2[b + off(m)], off(m) = m/1776 + 3*(m%1776).
// part[(j*NMC + mc)*256 + b] = sum_{mi<111} g2[b + off] * W1[j*7104 + mc*111 + mi]
__global__ __launch_bounds__(256)
void fc1_outer(const float* __restrict__ g2, const float* __restrict__ W1,
               float* __restrict__ part)
{
    __shared__ float W1s[NJ * MROW];   // 44.8 KB, padded rows
    __shared__ float g2w[400];
    const int tid = threadIdx.x;
    const int bt  = blockIdx.x >> 6;     // 0..3  (batch tile of 64)
    const int mc  = blockIdx.x & 63;     // 0..63 (m-chunk)

    // stage W1 chunk: rows j, cols mi in [mc*111, mc*111+111)
    for (int idx = tid; idx < NJ * MCH; idx += 256) {
        int j = idx / MCH, mi = idx % MCH;
        W1s[j * MROW + mi] = W1[(size_t)j * 7104 + mc * MCH + mi];
    }
    // stage g2 window: c = mc/16, k0 = (mc%16)*111; base = bt*64 + c + 3*k0
    const int c    = mc >> 4;
    const int k0   = (mc & 15) * MCH;
    const int base = bt * 64 + c + 3 * k0;
    for (int i = tid; i < 400; i += 256) {
        int gi = base + i;
        g2w[i] = (gi < NG2) ? g2[gi] : 0.f;   // max used index = base+393 <= 5583
    }
    __syncthreads();

    const int w = tid >> 6, l = tid & 63;    // wave w -> j in [25w, 25w+25); lane l = local batch
    float acc[25];
    #pragma unroll
    for (int jj = 0; jj < 25; ++jj) acc[jj] = 0.f;

    const float* wbase = W1s + (w * 25) * MROW;
    // groups of 4 mi (27 groups), float4 LDS reads of W1 rows; tail 3 scalar
    for (int m4 = 0; m4 < 27; ++m4) {
        const int mi = m4 * 4;
        const float g0 = g2w[l + 3 * (mi + 0)];
        const float g1 = g2w[l + 3 * (mi + 1)];
        const float g2v = g2w[l + 3 * (mi + 2)];
        const float g3 = g2w[l + 3 * (mi + 3)];
        #pragma unroll
        for (int jj = 0; jj < 25; ++jj) {
            const float4 wv = *reinterpret_cast<const float4*>(wbase + jj * MROW + mi);
            acc[jj] += g0 * wv.x + g1 * wv.y + g2v * wv.z + g3 * wv.w;
        }
    }
    #pragma unroll
    for (int mi = 108; mi < 111; ++mi) {
        const float gv = g2w[l + 3 * mi];
        #pragma unroll
        for (int jj = 0; jj < 25; ++jj)
            acc[jj] += gv * W1s[(w * 25 + jj) * MROW + mi];
    }

    const int b = bt * 64 + l;
    #pragma unroll
    for (int jj = 0; jj < 25; ++jj) {
        const int j = w * 25 + jj;
        part[(size_t)(j * NMC + mc) * 256 + b] = acc[jj];   // coalesced in l
    }
}

// ---- reduce partials -> a1[b*100 + j] = relu(fb1[j] + sum_mc part) ----
__global__ __launch_bounds__(256)
void fc1_reduce(const float* __restrict__ part, const float* __restrict__ fb1,
                float* __restrict__ a1)
{
    const int j = blockIdx.x;        // 0..99
    const int b = threadIdx.x;       // 0..255
    float s = 0.f;
    #pragma unroll 8
    for (int mc = 0; mc < NMC; ++mc)
        s += part[(size_t)(j * NMC + mc) * 256 + b];   // coalesced in b
    a1[b * NJ + j] = fmaxf(s + fb1[j], 0.f);
}

// ---- fc2 + log_softmax, one wave per batch ----
__global__ __launch_bounds__(64)
void fc2_out(const float* __restrict__ a1, const float* __restrict__ W2,
             const float* __restrict__ fb2, float* __restrict__ out)
{
    __shared__ float a1s[NJ];
    __shared__ float a2[CLS];
    const int tid = threadIdx.x;
    const int b   = blockIdx.x;

    for (int i = tid; i < NJ; i += 64) a1s[i] = a1[b * NJ + i];
    __syncthreads();

    if (tid < CLS) {
        float acc = fb2[tid];
        #pragma unroll 4
        for (int j = 0; j < NJ; ++j) acc += a1s[j] * W2[tid * NJ + j];
        a2[tid] = acc;
    }
    __syncthreads();

    if (tid < CLS) {
        float mx = -INFINITY;
        #pragma unroll
        for (int n = 0; n < CLS; ++n) mx = fmaxf(mx, a2[n]);
        float s = 0.f;
        #pragma unroll
        for (int n = 0; n < CLS; ++n) s += expf(a2[n] - mx);
        out[b * CLS + tid] = a2[tid] - mx - logf(s);
    }
}

extern "C" void kernel_launch(void* const* d_in, const int* in_sizes, int n_in,
                              void* d_out, int out_size, void* d_ws, size_t ws_size,
                              hipStream_t stream)
{
    const float* x   = (const float*)d_in[0];
    const float* w1  = (const float*)d_in[1];
    const float* b1  = (const float*)d_in[2];
    const float* t1  = (const float*)d_in[3];
    const float* w2  = (const float*)d_in[4];
    const float* b2  = (const float*)d_in[5];
    const float* t2  = (const float*)d_in[6];
    const float* fw1 = (const float*)d_in[7];
    const float* fb1 = (const float*)d_in[8];
    const float* fw2 = (const float*)d_in[9];
    const float* fb2 = (const float*)d_in[10];

    float* ws = (float*)d_ws;
    float* y1   = ws;                        // [N1]
    float* g    = ws + N1;                   // [N1]
    float* y2   = ws + 2 * N1;               // [2*N2]
    float* g2   = ws + 2 * N1 + 2 * N2;      // [NG2]
    float* part = g2 + NG2;                  // [100*64*256] = 6.55 MB
    float* a1   = part + (size_t)NJ * NMC * 256;  // [256*100]

    k1_conv1 <<<(N1 + 255) / 256, 256, 0, stream>>>(x, w1, b1, y1);
    k2_dil1  <<<(N1 + 255) / 256, 256, 0, stream>>>(y1, t1, g);
    k3_conv2 <<<(2 * N2 + 255) / 256, 256, 0, stream>>>(g, w2, b2, y2);
    k4_dil2  <<<(NG2 + 255) / 256, 256, 0, stream>>>(y2, t2, g2);
    fc1_outer<<<256, 256, 0, stream>>>(g2, fw1, part);
    fc1_reduce<<<NJ, 256, 0, stream>>>(part, fb1, a1);
    fc2_out  <<<256, 64, 0, stream>>>(a1, fw2, fb2, (float*)d_out);
}

// Round 13
// 43.593 us; speedup vs baseline: 2.5864x; 1.1836x over previous
//
#include <hip/hip_runtime.h>
#include <hip/hip_bf16.h>

#define N1   15996
#define N2   5328
#define NG2  5584
#define NJ   100
#define CLS  10
#define NMC  64
#define MCH  111     // 7104/64; 16*111 = 1776, chunks never cross c-boundary
#define MROW 112     // padded LDS row stride

// ---- KA: fused prep (k1+k2+k3+k4) with per-block windowed recompute ----
// Block -> single-channel g2 tile: bid<21 => c=0, p0=bid*256 (last tile 208);
// bid==21 => c=1, p0=0, 256 outputs. Chain: y1 -> g -> y2[c] -> g2[c].
__global__ __launch_bounds__(256)
void ka_prep(const float* __restrict__ x,  const float* __restrict__ w1,
             const float* __restrict__ b1, const float* __restrict__ t1,
             const float* __restrict__ w2, const float* __restrict__ b2,
             const float* __restrict__ t2, float* __restrict__ g2)
{
    __shared__ float Y1[804];
    __shared__ float G [800];
    __shared__ float Y2[264];
    const int tid = threadIdx.x;
    const int bid = blockIdx.x;

    int c, p0, cnt;
    if (bid < 21) { c = 0; p0 = bid * 256; cnt = (p0 + 256 <= N2) ? 256 : (N2 - p0); }
    else          { c = 1; p0 = 0;         cnt = 256; }

    const int q0 = (p0 - 3 > 0) ? p0 - 3 : 0;
    const int q1 = (p0 + cnt - 1 + 3 < N2 - 1) ? p0 + cnt - 1 + 3 : N2 - 1;
    const int nq = q1 - q0 + 1;                 // <= 262
    const int g0 = 3 * q0, g1 = 3 * q1 + 13;
    const int ng = g1 - g0 + 1;                 // <= 796 (g1 <= 15994 < N1)
    const int h0 = (g0 - 3 > 0) ? g0 - 3 : 0;
    const int h1 = (g1 + 3 < N1 - 1) ? g1 + 3 : N1 - 1;
    const int nh = h1 - h0 + 1;                 // <= 802

    // y1 window: y1[n] = relu(b1[0] + sum_k x[n+k]*w1[k]);  n+4 <= 15999 in-bounds
    for (int idx = tid; idx < nh; idx += 256) {
        const int n = h0 + idx;
        float acc = b1[0];
        #pragma unroll
        for (int k = 0; k < 5; ++k) acc += x[n + k] * w1[k];
        Y1[idx] = fmaxf(acc, 0.f);
    }
    __syncthreads();

    // g window: g[n] = max_d Y1[n+d-3] - (d-3)^2/(4 t1[0])
    {
        const float it1 = 1.f / (4.f * t1[0]);
        for (int idx = tid; idx < ng; idx += 256) {
            const int n = g0 + idx;
            float m = -INFINITY;
            #pragma unroll
            for (int d = 0; d < 7; ++d) {
                int p = n + d - 3;
                if ((unsigned)p < (unsigned)N1) {
                    float z = (float)(d - 3);
                    m = fmaxf(m, Y1[p - h0] - z * z * it1);
                }
            }
            G[idx] = m;
        }
    }
    __syncthreads();

    // y2 window (channel c): y2[q] = relu(b2[c] + sum_{i,k} G[i+3(q+k)] * w2[(c*2+i)*5+k])
    for (int idx = tid; idx < nq; idx += 256) {
        const int q = q0 + idx;
        float acc = b2[c];
        #pragma unroll
        for (int k = 0; k < 5; ++k) {
            #pragma unroll
            for (int i = 0; i < 2; ++i)
                acc += G[i + 3 * (q + k) - g0] * w2[(c * 2 + i) * 5 + k];
        }
        Y2[idx] = fmaxf(acc, 0.f);
    }
    __syncthreads();

    // g2 tile: g2[c*N2+p] = max_d Y2[p+d-3] - (d-3)^2/(4 t2[c])
    {
        const float it2 = 1.f / (4.f * t2[c]);
        for (int idx = tid; idx < cnt; idx += 256) {
            const int p = p0 + idx;
            float m = -INFINITY;
            #pragma unroll
            for (int d = 0; d < 7; ++d) {
                int q = p + d - 3;
                if ((unsigned)q < (unsigned)N2) {
                    float z = (float)(d - 3);
                    m = fmaxf(m, Y2[q - q0] - z * z * it2);
                }
            }
            g2[c * N2 + p] = m;
        }
    }
}

// ---- KB: fc1 outer-product; part layout [b][mc][j] via LDS transpose ----
__global__ __launch_bounds__(256)
void kb_fc1(const float* __restrict__ g2, const float* __restrict__ W1,
            float* __restrict__ part)
{
    __shared__ float lds[NJ * MROW + 400];   // W1s | g2w ; T overlays lds[0:6400]
    float* W1s = lds;
    float* g2w = lds + NJ * MROW;
    const int tid = threadIdx.x;
    const int bt  = blockIdx.x >> 6;
    const int mc  = blockIdx.x & 63;

    for (int idx = tid; idx < NJ * MCH; idx += 256) {
        int j = idx / MCH, mi = idx % MCH;
        W1s[j * MROW + mi] = W1[(size_t)j * 7104 + mc * MCH + mi];
    }
    const int c    = mc >> 4;
    const int k0   = (mc & 15) * MCH;
    const int base = bt * 64 + c + 3 * k0;
    for (int i = tid; i < 400; i += 256) {
        int gi = base + i;
        g2w[i] = (gi < NG2) ? g2[gi] : 0.f;   // max used = base+393 <= 5583
    }
    __syncthreads();

    const int w = tid >> 6, l = tid & 63;
    float acc[25];
    #pragma unroll
    for (int jj = 0; jj < 25; ++jj) acc[jj] = 0.f;

    const float* wbase = W1s + (w * 25) * MROW;
    for (int m4 = 0; m4 < 27; ++m4) {
        const int mi = m4 * 4;
        const float a0 = g2w[l + 3 * (mi + 0)];
        const float a1 = g2w[l + 3 * (mi + 1)];
        const float a2 = g2w[l + 3 * (mi + 2)];
        const float a3 = g2w[l + 3 * (mi + 3)];
        #pragma unroll
        for (int jj = 0; jj < 25; ++jj) {
            const float4 wv = *reinterpret_cast<const float4*>(wbase + jj * MROW + mi);
            acc[jj] += a0 * wv.x + a1 * wv.y + a2 * wv.z + a3 * wv.w;
        }
    }
    #pragma unroll
    for (int mi = 108; mi < 111; ++mi) {
        const float gv = g2w[l + 3 * mi];
        #pragma unroll
        for (int jj = 0; jj < 25; ++jj)
            acc[jj] += gv * W1s[(w * 25 + jj) * MROW + mi];
    }
    __syncthreads();                 // done reading W1s; reuse as T[6400]

    float* T = lds;
    #pragma unroll
    for (int jj = 0; jj < 25; ++jj)
        T[l * NJ + (w * 25 + jj)] = acc[jj];
    __syncthreads();

    // part[((bt*64+bl)*64 + mc)*100 + j]  -- contiguous 100-float runs
    for (int idx = tid; idx < 64 * NJ; idx += 256) {
        const int bl = idx / NJ, j = idx - bl * NJ;
        part[(size_t)((bt * 64 + bl) * NMC + mc) * NJ + j] = T[idx];
    }
}

// ---- KC: fused reduce + fc2 + log_softmax; block = batch row ----
__global__ __launch_bounds__(256)
void kc_out(const float* __restrict__ part, const float* __restrict__ fb1,
            const float* __restrict__ W2,  const float* __restrict__ fb2,
            float* __restrict__ out)
{
    __shared__ float S[NMC * NJ];    // 25.6 KB, contiguous read
    __shared__ float a1s[NJ];
    __shared__ float a2[CLS];
    const int tid = threadIdx.x;
    const int b   = blockIdx.x;

    const float* src = part + (size_t)b * NMC * NJ;
    for (int idx = tid; idx < NMC * NJ; idx += 256) S[idx] = src[idx];
    __syncthreads();

    if (tid < NJ) {
        float s = fb1[tid];
        #pragma unroll 8
        for (int mc = 0; mc < NMC; ++mc) s += S[mc * NJ + tid];
        a1s[tid] = fmaxf(s, 0.f);
    }
    __syncthreads();

    if (tid < CLS) {
        float acc = fb2[tid];
        #pragma unroll 4
        for (int j = 0; j < NJ; ++j) acc += a1s[j] * W2[tid * NJ + j];
        a2[tid] = acc;
    }
    __syncthreads();

    if (tid < CLS) {
        float mx = -INFINITY;
        #pragma unroll
        for (int n = 0; n < CLS; ++n) mx = fmaxf(mx, a2[n]);
        float s = 0.f;
        #pragma unroll
        for (int n = 0; n < CLS; ++n) s += expf(a2[n] - mx);
        out[b * CLS + tid] = a2[tid] - mx - logf(s);
    }
}

extern "C" void kernel_launch(void* const* d_in, const int* in_sizes, int n_in,
                              void* d_out, int out_size, void* d_ws, size_t ws_size,
                              hipStream_t stream)
{
    const float* x   = (const float*)d_in[0];
    const float* w1  = (const float*)d_in[1];
    const float* b1  = (const float*)d_in[2];
    const float* t1  = (const float*)d_in[3];
    const float* w2  = (const float*)d_in[4];
    const float* b2  = (const float*)d_in[5];
    const float* t2  = (const float*)d_in[6];
    const float* fw1 = (const float*)d_in[7];
    const float* fb1 = (const float*)d_in[8];
    const float* fw2 = (const float*)d_in[9];
    const float* fb2 = (const float*)d_in[10];

    float* ws   = (float*)d_ws;
    float* g2   = ws;                 // [NG2]
    float* part = ws + NG2;           // [256*64*100] = 6.55 MB

    ka_prep<<<22, 256, 0, stream>>>(x, w1, b1, t1, w2, b2, t2, g2);
    kb_fc1 <<<256, 256, 0, stream>>>(g2, fw1, part);
    kc_out <<<256, 256, 0, stream>>>(part, fb1, fw2, fb2, (float*)d_out);
}